// Round 3
// baseline (101.129 us; speedup 1.0000x reference)
//
#include <hip/hip_runtime.h>
#include <stdint.h>

// Log-sparse causal attention, B=4 L=2048 H=8 E=D=64, fp32 in/out.
// Allowed distances delta = q - j: {0..7, 9, 13, 21, 37, 69, 133, 261, 517, 1029}
//
// R7: 4 lanes/query x 16 dims/lane (was 8x8). Score reduction is now
// __shfl_xor 1,2 only -- both quad-perm DPP (VALU), no LDS-pipe swizzle, and
// cross-lane ops/query drop 6.4 -> 2.1. 128 queries/block at 512 threads:
// staging redundancy 1.58 -> 1.29 rows/query, half the blocks/barriers.
// SPAN=165 rows, LDS 89.8 KB -> 1 block/CU x 16 waves = 4 waves/SIMD (same
// occupancy as R6's 2x8). No launch_bounds min-occupancy arg and no register
// prefetch arrays (R5 lesson: (512,4) forced VGPR=64 -> 40 floats/thread
// scratch spill, WRITE_SIZE 73MB vs 17MB output).
// Row padded to 68 floats (272 B): row r starts at bank 4r mod 32 -> 8 row
// phases spread b128 reads across banks (PADF=64 would put every row at
// bank 0 -> 16-way conflict).

static constexpr int Bn = 4, Ln = 2048, Hn = 8, En = 64;
static constexpr int QPB = 128;           // queries per block
static constexpr int NT  = 512;           // threads per block (8 waves)
static constexpr int NEAR_MAX = 37;       // deltas <= this are staged
static constexpr int SPAN = NEAR_MAX + QPB;   // 165 rows: q0-37 .. q0+127
static constexpr int PADF = 68;           // floats per LDS row
static constexpr int NNEAR = 12;
static constexpr int NFAR  = 5;
static constexpr int NDELTA = NNEAR + NFAR;

__global__ __launch_bounds__(NT) void logsparse_attn_kernel(
    const float* __restrict__ Q,
    const float* __restrict__ K,
    const float* __restrict__ V,
    float* __restrict__ O)
{
    constexpr int nearD[NNEAR] = {0,1,2,3,4,5,6,7,9,13,21,37};
    constexpr int farD[NFAR]   = {69,133,261,517,1029};

    __shared__ float Ks[SPAN * PADF];
    __shared__ float Vs[SPAN * PADF];

    // 512 blocks = 32 (b,h) x 16 query-chunks; bh = blockIdx%32 keeps each
    // bh's 16 blocks on XCD (bh%8) under round-robin dispatch -> staging
    // overlap rows of consecutive chunks stay L2-local.
    const int bh = blockIdx.x & 31;
    const int l  = blockIdx.x >> 5;
    const int b  = bh >> 3;
    const int h  = bh & 7;
    const int q0 = l * QPB;

    const int tid = threadIdx.x;
    const size_t bhBase = ((size_t)b * Ln * Hn + (size_t)h) * (size_t)En;
    constexpr int ROWF = Hn * En;         // 512 floats between consecutive rows

    const int sub = tid & 3;              // 4 lanes per query, 16 dims each
    const int qq  = tid >> 2;             // query within block [0,128)
    const int q   = q0 + qq;
    const int dimOff = sub * 16;
    const size_t rowQ = bhBase + (size_t)q * ROWF + dimOff;

    // ---- issue Q loads first (independent of staging) ----
    const float4 q0v = *(const float4*)(Q + rowQ);
    const float4 q1v = *(const float4*)(Q + rowQ + 4);
    const float4 q2v = *(const float4*)(Q + rowQ + 8);
    const float4 q3v = *(const float4*)(Q + rowQ + 12);

    // ---- cooperative staging: 165 rows x 16 float4-chunks, K and V fused ----
    for (int idx = tid; idx < SPAN * 16; idx += NT) {
        const int rid = idx >> 4;
        const int ch  = idx & 15;
        int g = q0 - NEAR_MAX + rid;
        if (g < 0) g = 0;                 // finite data; masked later via p=0
        const size_t srcOff = bhBase + (size_t)g * ROWF + ch * 4;
        const int dst = rid * PADF + ch * 4;
        *(float4*)(Ks + dst) = *(const float4*)(K + srcOff);
        *(float4*)(Vs + dst) = *(const float4*)(V + srcOff);
    }

    // ---- Q chunk (16 floats), fold scale = 1/sqrt(64) ----
    const float qf[16] = {
        q0v.x*0.125f, q0v.y*0.125f, q0v.z*0.125f, q0v.w*0.125f,
        q1v.x*0.125f, q1v.y*0.125f, q1v.z*0.125f, q1v.w*0.125f,
        q2v.x*0.125f, q2v.y*0.125f, q2v.z*0.125f, q2v.w*0.125f,
        q3v.x*0.125f, q3v.y*0.125f, q3v.z*0.125f, q3v.w*0.125f };

    __syncthreads();

    // ---- scores: 12 near (LDS) + 5 far (global, inline loads) ----
    float sc[NDELTA];
    #pragma unroll
    for (int d = 0; d < NNEAR; ++d) {
        const int del = nearD[d];
        const float* kp = Ks + (qq + NEAR_MAX - del) * PADF + dimOff;
        const float4 k0 = *(const float4*)(kp);
        const float4 k1 = *(const float4*)(kp + 4);
        const float4 k2 = *(const float4*)(kp + 8);
        const float4 k3 = *(const float4*)(kp + 12);
        float s = qf[0]*k0.x + qf[1]*k0.y + qf[2]*k0.z  + qf[3]*k0.w
                + qf[4]*k1.x + qf[5]*k1.y + qf[6]*k1.z  + qf[7]*k1.w
                + qf[8]*k2.x + qf[9]*k2.y + qf[10]*k2.z + qf[11]*k2.w
                + qf[12]*k3.x+ qf[13]*k3.y+ qf[14]*k3.z + qf[15]*k3.w;
        s += __shfl_xor(s, 1);            // quad-perm DPP
        s += __shfl_xor(s, 2);            // quad-perm DPP
        sc[d] = (q - del < 0) ? -__builtin_inff() : s;
    }
    #pragma unroll
    for (int d = 0; d < NFAR; ++d) {
        const int del = farD[d];
        float s = -__builtin_inff();
        if (q0 + QPB - 1 >= del) {        // block-uniform: skip dead deltas
            const int j  = q - del;
            const int jc = (j < 0) ? 0 : j;   // p==0 later when j<0
            const float* kp = K + bhBase + (size_t)jc * ROWF + dimOff;
            const float4 k0 = *(const float4*)(kp);
            const float4 k1 = *(const float4*)(kp + 4);
            const float4 k2 = *(const float4*)(kp + 8);
            const float4 k3 = *(const float4*)(kp + 12);
            float t = qf[0]*k0.x + qf[1]*k0.y + qf[2]*k0.z  + qf[3]*k0.w
                    + qf[4]*k1.x + qf[5]*k1.y + qf[6]*k1.z  + qf[7]*k1.w
                    + qf[8]*k2.x + qf[9]*k2.y + qf[10]*k2.z + qf[11]*k2.w
                    + qf[12]*k3.x+ qf[13]*k3.y+ qf[14]*k3.z + qf[15]*k3.w;
            t += __shfl_xor(t, 1);
            t += __shfl_xor(t, 2);
            s = (j < 0) ? -__builtin_inff() : t;
        }
        sc[NNEAR + d] = s;
    }

    // ---- softmax over 17 scores; p overwrites sc (register economy) ----
    float m = sc[0];
    #pragma unroll
    for (int d = 1; d < NDELTA; ++d) m = fmaxf(m, sc[d]);
    float sum = 0.0f;
    #pragma unroll
    for (int d = 0; d < NDELTA; ++d) {
        sc[d] = __expf(sc[d] - m);        // exp(-inf)=0 for masked
        sum += sc[d];
    }
    const float inv = 1.0f / sum;

    // ---- weighted sum of V rows: near from LDS, far from global inline ----
    float acc[16] = {0,0,0,0,0,0,0,0,0,0,0,0,0,0,0,0};
    #pragma unroll
    for (int d = 0; d < NNEAR; ++d) {
        const int del = nearD[d];
        const float* vp = Vs + (qq + NEAR_MAX - del) * PADF + dimOff;
        const float4 v0 = *(const float4*)(vp);
        const float4 v1 = *(const float4*)(vp + 4);
        const float4 v2 = *(const float4*)(vp + 8);
        const float4 v3 = *(const float4*)(vp + 12);
        const float w = sc[d];
        acc[0]  = fmaf(w, v0.x, acc[0]);
        acc[1]  = fmaf(w, v0.y, acc[1]);
        acc[2]  = fmaf(w, v0.z, acc[2]);
        acc[3]  = fmaf(w, v0.w, acc[3]);
        acc[4]  = fmaf(w, v1.x, acc[4]);
        acc[5]  = fmaf(w, v1.y, acc[5]);
        acc[6]  = fmaf(w, v1.z, acc[6]);
        acc[7]  = fmaf(w, v1.w, acc[7]);
        acc[8]  = fmaf(w, v2.x, acc[8]);
        acc[9]  = fmaf(w, v2.y, acc[9]);
        acc[10] = fmaf(w, v2.z, acc[10]);
        acc[11] = fmaf(w, v2.w, acc[11]);
        acc[12] = fmaf(w, v3.x, acc[12]);
        acc[13] = fmaf(w, v3.y, acc[13]);
        acc[14] = fmaf(w, v3.z, acc[14]);
        acc[15] = fmaf(w, v3.w, acc[15]);
    }
    #pragma unroll
    for (int d = 0; d < NFAR; ++d) {
        const int del = farD[d];
        if (q0 + QPB - 1 >= del) {        // uniform; p==0 covers j<0 lanes
            const int j  = q - del;
            const int jc = (j < 0) ? 0 : j;
            const float* vp = V + bhBase + (size_t)jc * ROWF + dimOff;
            const float4 v0 = *(const float4*)(vp);
            const float4 v1 = *(const float4*)(vp + 4);
            const float4 v2 = *(const float4*)(vp + 8);
            const float4 v3 = *(const float4*)(vp + 12);
            const float w = sc[NNEAR + d];
            acc[0]  = fmaf(w, v0.x, acc[0]);
            acc[1]  = fmaf(w, v0.y, acc[1]);
            acc[2]  = fmaf(w, v0.z, acc[2]);
            acc[3]  = fmaf(w, v0.w, acc[3]);
            acc[4]  = fmaf(w, v1.x, acc[4]);
            acc[5]  = fmaf(w, v1.y, acc[5]);
            acc[6]  = fmaf(w, v1.z, acc[6]);
            acc[7]  = fmaf(w, v1.w, acc[7]);
            acc[8]  = fmaf(w, v2.x, acc[8]);
            acc[9]  = fmaf(w, v2.y, acc[9]);
            acc[10] = fmaf(w, v2.z, acc[10]);
            acc[11] = fmaf(w, v2.w, acc[11]);
            acc[12] = fmaf(w, v3.x, acc[12]);
            acc[13] = fmaf(w, v3.y, acc[13]);
            acc[14] = fmaf(w, v3.z, acc[14]);
            acc[15] = fmaf(w, v3.w, acc[15]);
        }
    }

    float4 o0, o1, o2, o3;
    o0.x = acc[0]*inv;  o0.y = acc[1]*inv;  o0.z = acc[2]*inv;  o0.w = acc[3]*inv;
    o1.x = acc[4]*inv;  o1.y = acc[5]*inv;  o1.z = acc[6]*inv;  o1.w = acc[7]*inv;
    o2.x = acc[8]*inv;  o2.y = acc[9]*inv;  o2.z = acc[10]*inv; o2.w = acc[11]*inv;
    o3.x = acc[12]*inv; o3.y = acc[13]*inv; o3.z = acc[14]*inv; o3.w = acc[15]*inv;
    *(float4*)(O + rowQ)      = o0;
    *(float4*)(O + rowQ + 4)  = o1;
    *(float4*)(O + rowQ + 8)  = o2;
    *(float4*)(O + rowQ + 12) = o3;
}

extern "C" void kernel_launch(void* const* d_in, const int* in_sizes, int n_in,
                              void* d_out, int out_size, void* d_ws, size_t ws_size,
                              hipStream_t stream) {
    const float* Q = (const float*)d_in[0];
    const float* K = (const float*)d_in[1];
    const float* V = (const float*)d_in[2];
    float* O = (float*)d_out;

    const int nblocks = Bn * Hn * (Ln / QPB);   // 512 blocks, 128 queries each
    logsparse_attn_kernel<<<nblocks, NT, 0, stream>>>(Q, K, V, O);
}